// Round 2
// baseline (54.642 us; speedup 1.0000x reference)
//
#include <hip/hip_runtime.h>

#define HW 65536
#define Bn 4
#define Mn 100
#define Dn 128

// One block per (scene b, grid row y): geometry -> flags -> sparse variance -> accumulate.
// Last block (global ticket) computes the final scalar.
__global__ __launch_bounds__(256) void fused_kernel(
    const float* __restrict__ atten, const float* __restrict__ boxes,
    float* __restrict__ gsum, float* __restrict__ gcnt,
    unsigned int* __restrict__ ticket, float* __restrict__ out)
{
    __shared__ float sbox[Mn * 20];
    __shared__ float ssum[Mn], scnt[Mn];
    __shared__ int   clist[256];
    __shared__ int   nflag;
    __shared__ int   lastblk;

    const int b  = blockIdx.x >> 8;
    const int y  = blockIdx.x & 255;
    const int tx = threadIdx.x;

    if (tx < Mn) { ssum[tx] = 0.0f; scnt[tx] = 0.0f; }
    if (tx == 0) nflag = 0;

    // ---- box geometry (exact same arithmetic as the verified round-1 geom_kernel)
    if (tx < Mn) {
        const float* bx = boxes + (size_t)(b * Mn + tx) * 7;
        float cx = bx[0], cy = bx[1];
        float l = bx[3], w = bx[4];
        float yaw = bx[6];
        const float DIMS0 = 51.2f + 51.2f;
        const float cellw = DIMS0 / 256.0f;
        float rl = fminf(fmaxf(cellw / l, 1.0f), 6.0f);
        float rw = fminf(fmaxf(cellw / w, 1.0f), 6.0f);
        float el = __fmul_rn(l, rl);
        float ew = __fmul_rn(w, rw);
        float c = cosf(yaw), s = sinf(yaw);
        const float nx[4] = {-0.5f, -0.5f, 0.5f, 0.5f};
        const float ny[4] = {-0.5f, 0.5f, 0.5f, -0.5f};
        float px[4], py[4];
        #pragma unroll
        for (int k = 0; k < 4; k++) {
            float ox = __fmul_rn(el, nx[k]);
            float oy = __fmul_rn(ew, ny[k]);
            float rx = __fadd_rn(__fmul_rn(ox, c), __fmul_rn(oy, s));
            float ry = __fadd_rn(__fmul_rn(-ox, s), __fmul_rn(oy, c));
            px[k] = __fadd_rn(rx, cx);
            py[k] = __fadd_rn(ry, cy);
        }
        float* o = sbox + tx * 20;
        #pragma unroll
        for (int k = 0; k < 4; k++) { o[k * 2] = px[k]; o[k * 2 + 1] = py[k]; }
        #pragma unroll
        for (int k = 0; k < 4; k++) {
            o[8 + k * 2]     = __fsub_rn(px[(k + 1) & 3], px[k]);
            o[8 + k * 2 + 1] = __fsub_rn(py[(k + 1) & 3], py[k]);
        }
        o[16] = cy;
        o[17] = 0.5f * sqrtf(el * el + ew * ew) + 0.01f;  // conservative prune radius
    }
    __syncthreads();

    // ---- per-cell parity-scan flag (x = tx; y shared by block -> prune is wave-uniform)
    const float DIMS0 = 51.2f + 51.2f;
    float gx = __fadd_rn(__fmul_rn((tx + 0.5f) * (1.0f / 256.0f), DIMS0), -51.2f);
    float gy = __fadd_rn(__fmul_rn((y + 0.5f) * (1.0f / 256.0f), DIMS0), -51.2f);

    int flag = -1;
    for (int m = 0; m < Mn; m++) {
        const float* o = &sbox[m * 20];
        if (fabsf(gy - o[16]) > o[17]) continue;
        bool ge = true, le = true;
        #pragma unroll
        for (int k = 0; k < 4; k++) {
            float dx = __fsub_rn(gx, o[k * 2]);
            float dy = __fsub_rn(gy, o[k * 2 + 1]);
            float cr = __fsub_rn(__fmul_rn(o[8 + k * 2], dy),
                                 __fmul_rn(o[8 + k * 2 + 1], dx));
            ge = ge && (cr >= 0.0f);
            le = le && (cr <= 0.0f);
        }
        if (ge || le) flag = (flag == -1) ? m : -1;
    }
    if (flag >= 0) {
        int idx = atomicAdd(&nflag, 1);
        clist[idx] = (flag << 8) | tx;   // flag<100 (7b) | x<256 (8b)
    }
    __syncthreads();
    const int n = nflag;

    // ---- variance ONLY for flagged cells: 32-lane group per row, float4/lane = 512B contiguous
    const int g = tx >> 5, lane = tx & 31;
    for (int i = g; i < n; i += 8) {
        int e = clist[i];
        int x = e & 255, m = e >> 8;
        const float4* p = reinterpret_cast<const float4*>(
            atten + (size_t)(b * HW + y * 256 + x) * Dn) + lane;
        float4 xv = *p;
        float s = xv.x + xv.y + xv.z + xv.w;
        float q = xv.x * xv.x + xv.y * xv.y + xv.z * xv.z + xv.w * xv.w;
        #pragma unroll
        for (int d = 16; d; d >>= 1) {
            s += __shfl_xor(s, d);
            q += __shfl_xor(q, d);
        }
        if (lane == 0) {
            float vv = (q - s * s * (1.0f / 128.0f)) * (1.0f / 127.0f);
            atomicAdd(&ssum[m], vv);
            atomicAdd(&scnt[m], 1.0f);
        }
    }
    __syncthreads();

    if (tx < Mn && scnt[tx] > 0.0f) {
        atomicAdd(&gsum[b * Mn + tx], ssum[tx]);
        atomicAdd(&gcnt[b * Mn + tx], scnt[tx]);
    }
    __syncthreads();

    // ---- ticket: last block finalizes
    if (tx == 0) {
        __threadfence();
        unsigned int t = __hip_atomic_fetch_add(ticket, 1u, __ATOMIC_ACQ_REL,
                                                __HIP_MEMORY_SCOPE_AGENT);
        lastblk = (t == (unsigned int)(gridDim.x - 1)) ? 1 : 0;
    }
    __syncthreads();
    if (!lastblk) return;
    __threadfence();

    float loss = 0.0f, num = 0.0f;
    for (int i = tx; i < Bn * Mn; i += 256) {
        float c = __hip_atomic_load(&gcnt[i], __ATOMIC_RELAXED, __HIP_MEMORY_SCOPE_AGENT);
        if (c > 0.0f) {
            float sL = __hip_atomic_load(&gsum[i], __ATOMIC_RELAXED, __HIP_MEMORY_SCOPE_AGENT);
            loss -= sL / fmaxf(c, 1.0f);
            num  += 1.0f;
        }
    }
    #pragma unroll
    for (int d = 32; d; d >>= 1) {
        loss += __shfl_xor(loss, d);
        num  += __shfl_xor(num, d);
    }
    if ((tx & 63) == 0) { ssum[tx >> 6] = loss; scnt[tx >> 6] = num; }
    __syncthreads();
    if (tx == 0) {
        float L = ssum[0] + ssum[1] + ssum[2] + ssum[3];
        float N = scnt[0] + scnt[1] + scnt[2] + scnt[3];
        out[0] = L / fmaxf(N, 1.0f);
    }
}

extern "C" void kernel_launch(void* const* d_in, const int* in_sizes, int n_in,
                              void* d_out, int out_size, void* d_ws, size_t ws_size,
                              hipStream_t stream) {
    const float* atten = (const float*)d_in[0];
    const float* boxes = (const float*)d_in[1];
    float* out = (float*)d_out;

    float* gsum = (float*)d_ws;                       // B*M floats
    float* gcnt = gsum + Bn * Mn;                     // B*M floats
    unsigned int* ticket = (unsigned int*)(gcnt + Bn * Mn);

    hipMemsetAsync(d_ws, 0, (size_t)(2 * Bn * Mn) * sizeof(float) + sizeof(unsigned int),
                   stream);
    fused_kernel<<<Bn * 256, 256, 0, stream>>>(atten, boxes, gsum, gcnt, ticket, out);
}